// Round 8
// baseline (186.823 us; speedup 1.0000x reference)
//
#include <hip/hip_runtime.h>

#define NB 32
#define ND 64
#define NT 4096
#define NK 512
#define NGRID 1024

typedef __attribute__((ext_vector_type(8))) short short8;
typedef __attribute__((ext_vector_type(16))) float f32x16;
typedef unsigned int uint32;
typedef unsigned short ushort16_t;

#define PERM(r) ((((r) & 7) * 16) + ((r) >> 3))
#define STR 68
#define ESTR 66
// acc-domain margin: bound = emax/2 + 2*eps_dot ~= 1.56e-4 (emax = 64/512^2).
// M2 = 2.5e-4 gives 1.6x safety; packed-quantization (<=6.1e-5) only WIDENS
// collection (round-down superset) and the p3-guard (more fallbacks) - safe.
#define M2 2.5e-4f
#define RCAP 4
#define NSLOT 16

__device__ __forceinline__ ushort16_t bf16rne(float f) {
    uint32 u = __float_as_uint(f);
    return (ushort16_t)((u + 0x7FFFu + ((u >> 16) & 1u)) >> 16);
}
__device__ __forceinline__ float bf16tof(ushort16_t h) {
    return __uint_as_float(((uint32)h) << 16);
}

// ---------------------------------------------------------------------------
// prep (verified R6-R8): blocks 0..15 pack cb into MFMA A-frags (bf16 hi/lo);
// block 16: exact numpy-pairwise enorm + zero loss slots/counter.
// ---------------------------------------------------------------------------
__global__ void prep_kernel(const float* __restrict__ cb,
                            uint4* __restrict__ cbfrag,
                            float* __restrict__ enorm,
                            double* __restrict__ loss_acc,
                            uint32* __restrict__ counter) {
    const int bi = blockIdx.x, tid = threadIdx.x;
    if (bi < 16) {
        const int t = bi * 256 + tid;
        const int c = t >> 8, rem = t & 255, s = rem >> 6, L = rem & 63;
        const int kcode = c * 32 + (L & 31);
        const int dbase = s * 16 + ((L >> 5) << 3);
        const float* src = cb + (size_t)kcode * 64 + dbase;
        const float4 pa = *(const float4*)src;
        const float4 pb = *(const float4*)(src + 4);
        const float f[8] = {pa.x, pa.y, pa.z, pa.w, pb.x, pb.y, pb.z, pb.w};
        uint32 hw[4], lw[4];
#pragma unroll
        for (int i = 0; i < 4; ++i) {
            const ushort16_t h0 = bf16rne(f[2*i]);
            const ushort16_t h1 = bf16rne(f[2*i+1]);
            const ushort16_t l0 = bf16rne(f[2*i]   - bf16tof(h0));
            const ushort16_t l1 = bf16rne(f[2*i+1] - bf16tof(h1));
            hw[i] = (uint32)h0 | ((uint32)h1 << 16);
            lw[i] = (uint32)l0 | ((uint32)l1 << 16);
        }
        cbfrag[(size_t)((c*4+s)*2 + 0)*64 + L] = make_uint4(hw[0],hw[1],hw[2],hw[3]);
        cbfrag[(size_t)((c*4+s)*2 + 1)*64 + L] = make_uint4(lw[0],lw[1],lw[2],lw[3]);
    } else {
        if (tid < NSLOT) loss_acc[tid] = 0.0;
        if (tid == 0) *counter = 0u;
        for (int k = tid; k < NK; k += 256) {
            const float* e = cb + (size_t)k * ND;
            float r[8];
#pragma unroll
            for (int j = 0; j < 8; ++j) {
                float s = __fmul_rn(e[j], e[j]);
#pragma unroll
                for (int i = 1; i < 8; ++i)
                    s = __fadd_rn(s, __fmul_rn(e[8*i+j], e[8*i+j]));
                r[j] = s;
            }
            enorm[k] = __fadd_rn(__fadd_rn(__fadd_rn(r[0],r[1]), __fadd_rn(r[2],r[3])),
                                 __fadd_rn(__fadd_rn(r[4],r[5]), __fadd_rn(r[6],r[7])));
        }
    }
}

// exact dist — the R1-R8 verified bit-exact chain
__device__ __forceinline__ float exact_dist(const float* __restrict__ zrow,
                                            const float* __restrict__ cb,
                                            const float* __restrict__ enl,
                                            float zn, int k2) {
    const float4* e4 = (const float4*)(cb + (size_t)k2 * ND);
    float a = 0.0f;
#pragma unroll
    for (int w = 0; w < 16; ++w) {
        const float4 ev = e4[w];
        const float4 zv = *(const float4*)(zrow + 4 * w);
        a = __builtin_fmaf(zv.x, ev.x, a);
        a = __builtin_fmaf(zv.y, ev.y, a);
        a = __builtin_fmaf(zv.z, ev.z, a);
        a = __builtin_fmaf(zv.w, ev.w, a);
    }
    return __fsub_rn(__fadd_rn(zn, enl[k2]), __fmul_rn(2.0f, a));
}

// ---------------------------------------------------------------------------
// R17 main: 128-thread blocks (2 waves); each wave screens 64 z-rows as TWO
// 32-row MFMA tiles sharing every A-fragment load: 8 A-loads feed 24 MFMAs
// (was 12) -> cbfrag L2 traffic per CU halves, per-iter ILP doubles (two
// independent 12-chains). Packed top-3 + register-rival resolution per tile
// (R16 logic duplicated via static-index unrolled t-loops). LDS unchanged
// -> 4 blocks/CU = 8 waves/CU, one dispatch round.
// ---------------------------------------------------------------------------
__global__ __launch_bounds__(128, 2) void vq_main(const float* __restrict__ z,
                                                  const float* __restrict__ cb,
                                                  const uint4* __restrict__ cbfrag,
                                                  const float* __restrict__ enorm,
                                                  float* __restrict__ qout,
                                                  float* __restrict__ idxout,
                                                  double* __restrict__ loss_acc,
                                                  uint32* __restrict__ counter,
                                                  float* __restrict__ out0) {
    __shared__ __align__(16) char smem[39968];
    float*       zl   = (float*)smem;              // 128 x STR (34816 B); later ech
    float*       enl  = (float*)(smem + 34816);    // 512 f32
    float*       znl  = (float*)(smem + 36864);    // 128 f32
    ushort16_t*  cand = (ushort16_t*)(smem + 37376); // 128 x 2 x RCAP u16 = 2048 B
    int*         sfin = (int*)(smem + 39424);      // 128
    double*      sred = (double*)(smem + 39936);   // 2 used

    const int bi    = blockIdx.x;                  // 1024
    const int b     = bi >> 5;
    const int tbase = (bi & 31) * 128;
    const int tid   = threadIdx.x;                 // 0..127
    const size_t zoff = (size_t)b * (ND * NT) + tbase;

    // ---- stage z (verified transpose; 128 threads -> 16 iters) ----
#pragma unroll
    for (int j = 0; j < 16; ++j) {
        const int qq = j * 128 + tid;
        const int i4 = qq & 31, d = qq >> 5;
        const float4 v = *(const float4*)(z + zoff + (size_t)d * NT + i4 * 4);
        const float vv[4] = {v.x, v.y, v.z, v.w};
#pragma unroll
        for (int c = 0; c < 4; ++c) {
            const int r = i4 * 4 + c;
            zl[PERM(r) * STR + d] = vv[c];
        }
    }
    for (int k = tid; k < NK; k += 128) enl[k] = enorm[k];
    __syncthreads();

    // ---- znorm (verified numpy pairwise; 128 threads = 128 rows) ----
    {
        const int r = tid;
        const float4* zr4 = (const float4*)&zl[PERM(r) * STR];
        float x[64];
#pragma unroll
        for (int wq = 0; wq < 16; ++wq) {
            const float4 t4 = zr4[wq];
            x[4*wq] = t4.x; x[4*wq+1] = t4.y; x[4*wq+2] = t4.z; x[4*wq+3] = t4.w;
        }
        float r8[8];
#pragma unroll
        for (int jj = 0; jj < 8; ++jj) {
            float s = __fmul_rn(x[jj], x[jj]);
#pragma unroll
            for (int ii = 1; ii < 8; ++ii)
                s = __fadd_rn(s, __fmul_rn(x[8*ii+jj], x[8*ii+jj]));
            r8[jj] = s;
        }
        znl[r] = __fadd_rn(__fadd_rn(__fadd_rn(r8[0],r8[1]), __fadd_rn(r8[2],r8[3])),
                           __fadd_rn(__fadd_rn(r8[4],r8[5]), __fadd_rn(r8[6],r8[7])));
    }

    // ---- B-frags for BOTH tiles (verified slot rule per tile) ----
    const int L    = tid & 63;
    const int w    = tid >> 6;                     // 0..1
    const int h    = L >> 5;
    const int rowl0 = w * 64 + (L & 31);           // tile 0 row
    const int rowl1 = rowl0 + 32;                  // tile 1 row
    short8 bhf0[4], blf0[4], bhf1[4], blf1[4];
    __syncthreads();   // znorm writes visible; zl stable hereafter
#pragma unroll
    for (int t = 0; t < 2; ++t) {
        const int rl = (t == 0) ? rowl0 : rowl1;
        const float* zrow = &zl[PERM(rl) * STR];
#pragma unroll
        for (int s = 0; s < 4; ++s) {
            const int d0 = s * 16 + h * 8;
            const float4 pa = *(const float4*)(zrow + d0);
            const float4 pb = *(const float4*)(zrow + d0 + 4);
            const float f[8] = {pa.x, pa.y, pa.z, pa.w, pb.x, pb.y, pb.z, pb.w};
            uint32 hw[4], lw[4];
#pragma unroll
            for (int i = 0; i < 4; ++i) {
                const ushort16_t h0 = bf16rne(f[2*i]);
                const ushort16_t h1 = bf16rne(f[2*i+1]);
                const ushort16_t l0 = bf16rne(f[2*i]   - bf16tof(h0));
                const ushort16_t l1 = bf16rne(f[2*i+1] - bf16tof(h1));
                hw[i] = (uint32)h0 | ((uint32)h1 << 16);
                lw[i] = (uint32)l0 | ((uint32)l1 << 16);
            }
            union { uint4 u; short8 s8; } uh, ul;
            uh.u = make_uint4(hw[0],hw[1],hw[2],hw[3]);
            ul.u = make_uint4(lw[0],lw[1],lw[2],lw[3]);
            if (t == 0) { bhf0[s] = uh.s8; blf0[s] = ul.s8; }
            else        { bhf1[s] = uh.s8; blf1[s] = ul.s8; }
        }
    }

    const int h4 = h * 4;

    // ---- ONE-pass screen: two tiles per A-load, packed top-3 per tile ----
    uint32 P1[2] = {0u, 0u}, P2[2] = {0u, 0u}, P3[2] = {0u, 0u};
#pragma unroll 2
    for (int c = 0; c < 16; ++c) {
        uint4 B[8];
#pragma unroll
        for (int p = 0; p < 8; ++p) B[p] = cbfrag[(size_t)((c * 8 + p) * 64) + L];
        f32x16 A0, A1;
#pragma unroll
        for (int r = 0; r < 16; ++r) { A0[r] = 0.0f; A1[r] = 0.0f; }
#pragma unroll
        for (int s = 0; s < 4; ++s) {
            union { uint4 u; short8 s8; } ah, al;
            ah.u = B[s * 2 + 0];
            al.u = B[s * 2 + 1];
            A0 = __builtin_amdgcn_mfma_f32_32x32x16_bf16(ah.s8, bhf0[s], A0, 0, 0, 0);
            A1 = __builtin_amdgcn_mfma_f32_32x32x16_bf16(ah.s8, bhf1[s], A1, 0, 0, 0);
            A0 = __builtin_amdgcn_mfma_f32_32x32x16_bf16(al.s8, bhf0[s], A0, 0, 0, 0);
            A1 = __builtin_amdgcn_mfma_f32_32x32x16_bf16(al.s8, bhf1[s], A1, 0, 0, 0);
            A0 = __builtin_amdgcn_mfma_f32_32x32x16_bf16(ah.s8, blf0[s], A0, 0, 0, 0);
            A1 = __builtin_amdgcn_mfma_f32_32x32x16_bf16(ah.s8, blf1[s], A1, 0, 0, 0);
        }
#pragma unroll
        for (int r = 0; r < 16; ++r) {
            const int kc = c * 32 + ((r & 3) + 8 * (r >> 2)) + h4;
            {
                const uint32 pv = (__float_as_uint(fmaxf(A0[r] + 1.0f, 0.0f)) & ~0x1FFu)
                                | (uint32)kc;
                const bool g1 = pv > P1[0], g2 = pv > P2[0], g3 = pv > P3[0];
                P3[0] = g2 ? P2[0] : (g3 ? pv : P3[0]);
                P2[0] = g1 ? P1[0] : (g2 ? pv : P2[0]);
                P1[0] = g1 ? pv : P1[0];
            }
            {
                const uint32 pv = (__float_as_uint(fmaxf(A1[r] + 1.0f, 0.0f)) & ~0x1FFu)
                                | (uint32)kc;
                const bool g1 = pv > P1[1], g2 = pv > P2[1], g3 = pv > P3[1];
                P3[1] = g2 ? P2[1] : (g3 ? pv : P3[1]);
                P2[1] = g1 ? P1[1] : (g2 ? pv : P2[1]);
                P1[1] = g1 ? pv : P1[1];
            }
        }
    }

    // ---- cross-half combine + thresholds (per tile) ----
    int    kG[2], iown[2];
    uint32 thrF[2];
#pragma unroll
    for (int t = 0; t < 2; ++t) {
        const uint32 op1 = __shfl_xor(P1[t], 32);
        const uint32 pk  = (P1[t] > op1) ? P1[t] : op1;  // value-ties force rivals
        kG[t] = (int)(pk & 0x1FFu);
        const float bm   = __uint_as_float(pk & ~0x1FFu) - 1.0f;
        const float thrf = bm - M2;
        thrF[t] = __float_as_uint(fmaxf(thrf + 1.0f, 0.0f)) & ~0x1FFu;
        iown[t] = (((kG[t] >> 2) & 1) == h);
    }

    const float* zrowR[2] = { &zl[PERM(rowl0) * STR], &zl[PERM(rowl1) * STR] };
    const float  znR[2]   = { znl[rowl0], znl[rowl1] };

    int bkf[2];
    if (__any((int)(P3[0] >= thrF[0]) | (int)(P3[1] >= thrF[1]))) {
        // ---- rare wave: re-screen collecting rivals for both tiles ----
        int myc[2] = {0, 0}, ovf = 0;
        ushort16_t* ml[2] = { cand + (rowl0 * 2 + h) * RCAP,
                              cand + (rowl1 * 2 + h) * RCAP };
#pragma unroll 1
        for (int c = 0; c < 16; ++c) {
            uint4 B[8];
#pragma unroll
            for (int p = 0; p < 8; ++p) B[p] = cbfrag[(size_t)((c * 8 + p) * 64) + L];
            f32x16 A0, A1;
#pragma unroll
            for (int r = 0; r < 16; ++r) { A0[r] = 0.0f; A1[r] = 0.0f; }
#pragma unroll
            for (int s = 0; s < 4; ++s) {
                union { uint4 u; short8 s8; } ah, al;
                ah.u = B[s * 2 + 0];
                al.u = B[s * 2 + 1];
                A0 = __builtin_amdgcn_mfma_f32_32x32x16_bf16(ah.s8, bhf0[s], A0, 0, 0, 0);
                A1 = __builtin_amdgcn_mfma_f32_32x32x16_bf16(ah.s8, bhf1[s], A1, 0, 0, 0);
                A0 = __builtin_amdgcn_mfma_f32_32x32x16_bf16(al.s8, bhf0[s], A0, 0, 0, 0);
                A1 = __builtin_amdgcn_mfma_f32_32x32x16_bf16(al.s8, bhf1[s], A1, 0, 0, 0);
                A0 = __builtin_amdgcn_mfma_f32_32x32x16_bf16(ah.s8, blf0[s], A0, 0, 0, 0);
                A1 = __builtin_amdgcn_mfma_f32_32x32x16_bf16(ah.s8, blf1[s], A1, 0, 0, 0);
            }
#pragma unroll
            for (int r = 0; r < 16; ++r) {
                const int kc = c * 32 + ((r & 3) + 8 * (r >> 2)) + h4;
#pragma unroll
                for (int t = 0; t < 2; ++t) {
                    const float av = (t == 0) ? A0[r] : A1[r];
                    const uint32 pv = (__float_as_uint(fmaxf(av + 1.0f, 0.0f)) & ~0x1FFu)
                                    | (uint32)kc;
                    if (pv >= thrF[t] && kc != kG[t]) {
                        if (myc[t] < RCAP) ml[t][myc[t]++] = (ushort16_t)kc;
                        else ovf = 1;
                    }
                }
            }
        }
        const int aovf = ovf | __shfl_xor(ovf, 32);
#pragma unroll
        for (int t = 0; t < 2; ++t) {
            const int totr = myc[t] + __shfl_xor(myc[t], 32);
            if (aovf) {
                float bd = __builtin_inff(); int bq = 0x7FFFFFFF;
                for (int c = 0; c < 16; ++c)
#pragma unroll
                    for (int qd = 0; qd < 4; ++qd)
#pragma unroll
                        for (int i = 0; i < 4; ++i) {
                            const int k2c = c * 32 + qd * 8 + h * 4 + i;
                            const float dv = exact_dist(zrowR[t], cb, enl, znR[t], k2c);
                            if (dv < bd || (dv == bd && k2c < bq)) { bd = dv; bq = k2c; }
                        }
                const float obd = __shfl_xor(bd, 32);
                const int   obq = __shfl_xor(bq, 32);
                bkf[t] = (obd < bd || (obd == bd && obq < bq)) ? obq : bq;
            } else if (totr > 0) {
                float bd = __builtin_inff(); int bq = 0x7FFFFFFF;
                if (iown[t]) { bd = exact_dist(zrowR[t], cb, enl, znR[t], kG[t]); bq = kG[t]; }
                for (int i = 0; i < myc[t]; ++i) {
                    const int k2c = ml[t][i];
                    const float dv = exact_dist(zrowR[t], cb, enl, znR[t], k2c);
                    if (dv < bd || (dv == bd && k2c < bq)) { bd = dv; bq = k2c; }
                }
                const float obd = __shfl_xor(bd, 32);
                const int   obq = __shfl_xor(bq, 32);
                bkf[t] = (obd < bd || (obd == bd && obq < bq)) ? obq : bq;
            } else {
                bkf[t] = kG[t];
            }
        }
    } else {
        // ---- common wave: rivals already in registers, per tile ----
#pragma unroll
        for (int t = 0; t < 2; ++t) {
            const int k1 = (int)(P1[t] & 0x1FFu);
            const int k2 = (int)(P2[t] & 0x1FFu);
            const int r1v = (!iown[t]) && (P1[t] >= thrF[t]);  // losing half's best
            const int r2v = (P2[t] >= thrF[t]);
            const int nr  = r1v + r2v;
            const int totr = nr + __shfl_xor(nr, 32);
            if (totr > 0) {
                float bd = __builtin_inff(); int bq = 0x7FFFFFFF;
                if (iown[t]) { bd = exact_dist(zrowR[t], cb, enl, znR[t], kG[t]); bq = kG[t]; }
                if (r1v) {
                    const float dv = exact_dist(zrowR[t], cb, enl, znR[t], k1);
                    if (dv < bd || (dv == bd && k1 < bq)) { bd = dv; bq = k1; }
                }
                if (r2v) {
                    const float dv = exact_dist(zrowR[t], cb, enl, znR[t], k2);
                    if (dv < bd || (dv == bd && k2 < bq)) { bd = dv; bq = k2; }
                }
                const float obd = __shfl_xor(bd, 32);
                const int   obq = __shfl_xor(bq, 32);
                bkf[t] = (obd < bd || (obd == bd && obq < bq)) ? obq : bq;
            } else {
                bkf[t] = kG[t];          // no rival: screen best is proven
            }
        }
    }

    if (h == 0) {
        sfin[rowl0] = bkf[0];
        sfin[rowl1] = bkf[1];
        idxout[(size_t)b * NT + tbase + rowl0] = (float)bkf[0];
        idxout[(size_t)b * NT + tbase + rowl1] = (float)bkf[1];
    }
    __syncthreads();

    // ---- staged epilogue: ech build (R8 math; 128 threads -> 16 iters) ----
    float* ech = zl;
#pragma unroll
    for (int j = 0; j < 16; ++j) {
        const int qq  = j * 128 + tid;
        const int row = qq >> 4, d4 = qq & 15;
        const float4 v = *(const float4*)(cb + (size_t)sfin[row] * ND + d4 * 4);
        float* dst = &ech[row * ESTR + d4 * 4];
        *(float2*)(dst)     = make_float2(v.x, v.y);
        *(float2*)(dst + 2) = make_float2(v.z, v.w);
    }
    __syncthreads();

    // ---- loss + qout: float4-vectorized (same per-element arithmetic) ----
    double lsum = 0.0;
#pragma unroll 4
    for (int j = 0; j < 16; ++j) {
        const int qq  = j * 128 + tid;
        const int ir0 = (qq & 31) * 4, d = qq >> 5;
        const float4 zv4 = *(const float4*)(z + zoff + (size_t)d * NT + ir0);
        const float zv[4] = {zv4.x, zv4.y, zv4.z, zv4.w};
        float qo[4];
#pragma unroll
        for (int m = 0; m < 4; ++m) {
            const float ev = ech[(ir0 + m) * ESTR + d];
            const float diff = __fsub_rn(ev, zv[m]);       // quantized - zt
            qo[m] = __fadd_rn(zv[m], diff);
            lsum += (double)diff * (double)diff;
        }
        *(float4*)(qout + (size_t)b * (ND*NT) + (size_t)d * NT + tbase + ir0) =
            make_float4(qo[0], qo[1], qo[2], qo[3]);
    }
#pragma unroll
    for (int off = 32; off > 0; off >>= 1) lsum += __shfl_down(lsum, off, 64);
    if ((tid & 63) == 0) sred[tid >> 6] = lsum;
    __syncthreads();

    if (tid == 0) {
        const double bsum = sred[0] + sred[1];
        atomicAdd(loss_acc + (bi & (NSLOT - 1)), bsum);
        __threadfence();
        const uint32 old = atomicAdd(counter, 1u);
        if (old == (uint32)(NGRID - 1)) {
            __threadfence();
            double tot = 0.0;
            for (int i = 0; i < NSLOT; ++i)
                tot += ((volatile double*)loss_acc)[i];
            const double m = tot / (double)((size_t)NB * NT * ND);
            out0[0] = (float)(1.25 * m);   // codebook + 0.25*commitment
        }
    }
}

extern "C" void kernel_launch(void* const* d_in, const int* in_sizes, int n_in,
                              void* d_out, int out_size, void* d_ws, size_t ws_size,
                              hipStream_t stream) {
    const float* z  = (const float*)d_in[0];
    const float* cb = (const float*)d_in[1];

    float* out      = (float*)d_out;
    float* loss_out = out;                                  // 1 elem
    float* qout     = out + 1;                              // B*D*T
    float* idxout   = out + 1 + (size_t)NB * ND * NT;       // B*T

    uint4*  cbfrag   = (uint4*)d_ws;
    float*  enorm    = (float*)((char*)d_ws + 139264);      // 2048 B
    double* loss_acc = (double*)((char*)d_ws + 141312);     // 16 x 8 B
    uint32* counter  = (uint32*)((char*)d_ws + 141440);     // 4 B

    prep_kernel<<<17, 256, 0, stream>>>(cb, cbfrag, enorm, loss_acc, counter);
    vq_main<<<NGRID, 128, 0, stream>>>(z, cb, cbfrag, enorm, qout, idxout,
                                       loss_acc, counter, loss_out);
}

// Round 9
// 176.129 us; speedup vs baseline: 1.0607x; 1.0607x over previous
//
#include <hip/hip_runtime.h>

#define NB 32
#define ND 64
#define NT 4096
#define NK 512
#define NGRID 1024

typedef __attribute__((ext_vector_type(8))) short short8;
typedef __attribute__((ext_vector_type(16))) float f32x16;
typedef unsigned int uint32;
typedef unsigned short ushort16_t;

#define PERM(r) ((((r) & 7) * 16) + ((r) >> 3))
#define STR 68
#define ESTR 66
// acc-domain margin: bound = emax/2 + 2*eps_dot ~= 1.56e-4 (emax = 64/512^2).
// M2 = 2.5e-4 gives 1.6x safety; packed-quantization (<=6.1e-5) only WIDENS
// collection (round-down superset) and the p3-guard (more fallbacks) - safe.
#define M2 2.5e-4f
#define RCAP 4
#define NSLOT 16

__device__ __forceinline__ ushort16_t bf16rne(float f) {
    uint32 u = __float_as_uint(f);
    return (ushort16_t)((u + 0x7FFFu + ((u >> 16) & 1u)) >> 16);
}
__device__ __forceinline__ float bf16tof(ushort16_t h) {
    return __uint_as_float(((uint32)h) << 16);
}

// ---------------------------------------------------------------------------
// prep (verified R6-R8): blocks 0..15 pack cb into MFMA A-frags (bf16 hi/lo);
// block 16: exact numpy-pairwise enorm + zero loss slots/counter.
// ---------------------------------------------------------------------------
__global__ void prep_kernel(const float* __restrict__ cb,
                            uint4* __restrict__ cbfrag,
                            float* __restrict__ enorm,
                            double* __restrict__ loss_acc,
                            uint32* __restrict__ counter) {
    const int bi = blockIdx.x, tid = threadIdx.x;
    if (bi < 16) {
        const int t = bi * 256 + tid;
        const int c = t >> 8, rem = t & 255, s = rem >> 6, L = rem & 63;
        const int kcode = c * 32 + (L & 31);
        const int dbase = s * 16 + ((L >> 5) << 3);
        const float* src = cb + (size_t)kcode * 64 + dbase;
        const float4 pa = *(const float4*)src;
        const float4 pb = *(const float4*)(src + 4);
        const float f[8] = {pa.x, pa.y, pa.z, pa.w, pb.x, pb.y, pb.z, pb.w};
        uint32 hw[4], lw[4];
#pragma unroll
        for (int i = 0; i < 4; ++i) {
            const ushort16_t h0 = bf16rne(f[2*i]);
            const ushort16_t h1 = bf16rne(f[2*i+1]);
            const ushort16_t l0 = bf16rne(f[2*i]   - bf16tof(h0));
            const ushort16_t l1 = bf16rne(f[2*i+1] - bf16tof(h1));
            hw[i] = (uint32)h0 | ((uint32)h1 << 16);
            lw[i] = (uint32)l0 | ((uint32)l1 << 16);
        }
        cbfrag[(size_t)((c*4+s)*2 + 0)*64 + L] = make_uint4(hw[0],hw[1],hw[2],hw[3]);
        cbfrag[(size_t)((c*4+s)*2 + 1)*64 + L] = make_uint4(lw[0],lw[1],lw[2],lw[3]);
    } else {
        if (tid < NSLOT) loss_acc[tid] = 0.0;
        if (tid == 0) *counter = 0u;
        for (int k = tid; k < NK; k += 256) {
            const float* e = cb + (size_t)k * ND;
            float r[8];
#pragma unroll
            for (int j = 0; j < 8; ++j) {
                float s = __fmul_rn(e[j], e[j]);
#pragma unroll
                for (int i = 1; i < 8; ++i)
                    s = __fadd_rn(s, __fmul_rn(e[8*i+j], e[8*i+j]));
                r[j] = s;
            }
            enorm[k] = __fadd_rn(__fadd_rn(__fadd_rn(r[0],r[1]), __fadd_rn(r[2],r[3])),
                                 __fadd_rn(__fadd_rn(r[4],r[5]), __fadd_rn(r[6],r[7])));
        }
    }
}

// exact dist — the R1-R8 verified bit-exact chain
__device__ __forceinline__ float exact_dist(const float* __restrict__ zrow,
                                            const float* __restrict__ cb,
                                            const float* __restrict__ enl,
                                            float zn, int k2) {
    const float4* e4 = (const float4*)(cb + (size_t)k2 * ND);
    float a = 0.0f;
#pragma unroll
    for (int w = 0; w < 16; ++w) {
        const float4 ev = e4[w];
        const float4 zv = *(const float4*)(zrow + 4 * w);
        a = __builtin_fmaf(zv.x, ev.x, a);
        a = __builtin_fmaf(zv.y, ev.y, a);
        a = __builtin_fmaf(zv.z, ev.z, a);
        a = __builtin_fmaf(zv.w, ev.w, a);
    }
    return __fsub_rn(__fadd_rn(zn, enl[k2]), __fmul_rn(2.0f, a));
}

// lazy znorm: bit-identical to the verified numpy-pairwise chain.
// flat index f = 4*wq + m ascends 0..63 => for each jj = f&7, ii = f>>3
// ascends 0..7 in program order — same summation order as the original.
__device__ __forceinline__ float znorm_of(const float* __restrict__ zrow) {
    float r8[8];
    const float4* zr4 = (const float4*)zrow;
#pragma unroll
    for (int wq = 0; wq < 16; ++wq) {
        const float4 t4 = zr4[wq];
        const float v[4] = {t4.x, t4.y, t4.z, t4.w};
#pragma unroll
        for (int m = 0; m < 4; ++m) {
            const int f = 4 * wq + m;
            const int jj = f & 7;
            if (f < 8) r8[jj] = __fmul_rn(v[m], v[m]);
            else       r8[jj] = __fadd_rn(r8[jj], __fmul_rn(v[m], v[m]));
        }
    }
    return __fadd_rn(__fadd_rn(__fadd_rn(r8[0],r8[1]), __fadd_rn(r8[2],r8[3])),
                     __fadd_rn(__fadd_rn(r8[4],r8[5]), __fadd_rn(r8[6],r8[7])));
}

// ---------------------------------------------------------------------------
// R18 main: R16's one-pass packed-top-3 screen with (1) the R13 register
// double-buffer prefetch restored (next 8KB chunk loads issue while current
// chunk computes — the only structural loss from the R13->R15 rewrite),
// (2) znorm computed lazily inside the resolution branches (only ~10% of
// lanes need it; deletes a whole phase + znl buffer), (3) R15's scalar loss
// epilogue restored (R16's float4 form added 1.6M LDS bank conflicts).
// Rival logic, exact chain, ech staging: verified verbatim.
// ---------------------------------------------------------------------------
__global__ __launch_bounds__(256, 3) void vq_main(const float* __restrict__ z,
                                                  const float* __restrict__ cb,
                                                  const uint4* __restrict__ cbfrag,
                                                  const float* __restrict__ enorm,
                                                  float* __restrict__ qout,
                                                  float* __restrict__ idxout,
                                                  double* __restrict__ loss_acc,
                                                  uint32* __restrict__ counter,
                                                  float* __restrict__ out0) {
    __shared__ __align__(16) char smem[39456];
    float*       zl   = (float*)smem;              // 128 x STR (34816 B); later ech
    float*       enl  = (float*)(smem + 34816);    // 512 f32
    ushort16_t*  cand = (ushort16_t*)(smem + 36864); // 128 x 2 x RCAP u16 = 2048 B
    int*         sfin = (int*)(smem + 38912);      // 128
    double*      sred = (double*)(smem + 39424);   // 4

    const int bi    = blockIdx.x;                  // 1024
    const int b     = bi >> 5;
    const int tbase = (bi & 31) * 128;
    const int tid   = threadIdx.x;
    const size_t zoff = (size_t)b * (ND * NT) + tbase;

    // ---- stage z (verified transpose) ----
#pragma unroll
    for (int j = 0; j < 8; ++j) {
        const int qq = j * 256 + tid;
        const int i4 = qq & 31, d = qq >> 5;
        const float4 v = *(const float4*)(z + zoff + (size_t)d * NT + i4 * 4);
        const float vv[4] = {v.x, v.y, v.z, v.w};
#pragma unroll
        for (int c = 0; c < 4; ++c) {
            const int r = i4 * 4 + c;
            zl[PERM(r) * STR + d] = vv[c];
        }
    }
    for (int k = tid; k < NK; k += 256) enl[k] = enorm[k];
    __syncthreads();

    // ---- B-frags (verified: z rows bf16 hi/lo, same slot->d rule as prep) ----
    const int L    = tid & 63;
    const int w    = tid >> 6;
    const int h    = L >> 5;
    const int rowl = w * 32 + (L & 31);
    short8 bhf[4], blf[4];
    {
        const float* zrow = &zl[PERM(rowl) * STR];
#pragma unroll
        for (int s = 0; s < 4; ++s) {
            const int d0 = s * 16 + h * 8;
            const float4 pa = *(const float4*)(zrow + d0);
            const float4 pb = *(const float4*)(zrow + d0 + 4);
            const float f[8] = {pa.x, pa.y, pa.z, pa.w, pb.x, pb.y, pb.z, pb.w};
            uint32 hw[4], lw[4];
#pragma unroll
            for (int i = 0; i < 4; ++i) {
                const ushort16_t h0 = bf16rne(f[2*i]);
                const ushort16_t h1 = bf16rne(f[2*i+1]);
                const ushort16_t l0 = bf16rne(f[2*i]   - bf16tof(h0));
                const ushort16_t l1 = bf16rne(f[2*i+1] - bf16tof(h1));
                hw[i] = (uint32)h0 | ((uint32)h1 << 16);
                lw[i] = (uint32)l0 | ((uint32)l1 << 16);
            }
            union { uint4 u; short8 s8; } uh, ul;
            uh.u = make_uint4(hw[0],hw[1],hw[2],hw[3]);
            ul.u = make_uint4(lw[0],lw[1],lw[2],lw[3]);
            bhf[s] = uh.s8; blf[s] = ul.s8;
        }
    }

    const int h4 = h * 4;

    // ---- ONE-pass screen: packed top-3, branchless, dbuf-prefetched ----
    uint32 p1 = 0u, p2 = 0u, p3 = 0u;   // sorted desc; 0 acts as -inf
    {
        uint4 buf0[8], buf1[8];
#pragma unroll
        for (int p = 0; p < 8; ++p) buf0[p] = cbfrag[(size_t)p * 64 + L];
#pragma unroll 2
        for (int c = 0; c < 16; ++c) {
            const uint4* cur = (c & 1) ? buf1 : buf0;
            uint4*       nxt = (c & 1) ? buf0 : buf1;
#pragma unroll
            for (int p = 0; p < 8; ++p)            // c=15 prefetch hits ws slack
                nxt[p] = cbfrag[(size_t)((c + 1) * 8 + p) * 64 + L];
            f32x16 acc;
#pragma unroll
            for (int r = 0; r < 16; ++r) acc[r] = 0.0f;
#pragma unroll
            for (int s = 0; s < 4; ++s) {
                union { uint4 u; short8 s8; } ah, al;
                ah.u = cur[s * 2 + 0];
                al.u = cur[s * 2 + 1];
                acc = __builtin_amdgcn_mfma_f32_32x32x16_bf16(ah.s8, bhf[s], acc, 0, 0, 0);
                acc = __builtin_amdgcn_mfma_f32_32x32x16_bf16(al.s8, bhf[s], acc, 0, 0, 0);
                acc = __builtin_amdgcn_mfma_f32_32x32x16_bf16(ah.s8, blf[s], acc, 0, 0, 0);
            }
#pragma unroll
            for (int r = 0; r < 16; ++r) {
                const int kc = c * 32 + ((r & 3) + 8 * (r >> 2)) + h4;
                const uint32 pv = (__float_as_uint(fmaxf(acc[r] + 1.0f, 0.0f)) & ~0x1FFu)
                                | (uint32)kc;
                const bool g1 = pv > p1, g2 = pv > p2, g3 = pv > p3;
                p3 = g2 ? p2 : (g3 ? pv : p3);
                p2 = g1 ? p1 : (g2 ? pv : p2);
                p1 = g1 ? pv : p1;
            }
        }
    }

    // ---- cross-half combine + threshold ----
    const uint32 op1 = __shfl_xor(p1, 32);
    const uint32 pkG = (p1 > op1) ? p1 : op1;    // value-ties force rivals below
    const int    kG  = (int)(pkG & 0x1FFu);
    const float  bm   = __uint_as_float(pkG & ~0x1FFu) - 1.0f;
    const float  thrf = bm - M2;
    const uint32 thrF = __float_as_uint(fmaxf(thrf + 1.0f, 0.0f)) & ~0x1FFu;

    const float* zrow = &zl[PERM(rowl) * STR];
    const int    iown = (((kG >> 2) & 1) == h);

    int bkf;
    if (__any((int)(p3 >= thrF))) {
        // ---- rare wave: top-3 may be incomplete -> barrier-free collect ----
        int myc = 0, ovf = 0;
        ushort16_t* mylist = cand + (rowl * 2 + h) * RCAP;
#pragma unroll 1
        for (int c = 0; c < 16; ++c) {
            uint4 B[8];
#pragma unroll
            for (int p = 0; p < 8; ++p) B[p] = cbfrag[(size_t)((c * 8 + p) * 64) + L];
            f32x16 acc;
#pragma unroll
            for (int r = 0; r < 16; ++r) acc[r] = 0.0f;
#pragma unroll
            for (int s = 0; s < 4; ++s) {
                union { uint4 u; short8 s8; } ah, al;
                ah.u = B[s * 2 + 0];
                al.u = B[s * 2 + 1];
                acc = __builtin_amdgcn_mfma_f32_32x32x16_bf16(ah.s8, bhf[s], acc, 0, 0, 0);
                acc = __builtin_amdgcn_mfma_f32_32x32x16_bf16(al.s8, bhf[s], acc, 0, 0, 0);
                acc = __builtin_amdgcn_mfma_f32_32x32x16_bf16(ah.s8, blf[s], acc, 0, 0, 0);
            }
#pragma unroll
            for (int r = 0; r < 16; ++r) {
                const int kc = c * 32 + ((r & 3) + 8 * (r >> 2)) + h4;
                const uint32 pv = (__float_as_uint(fmaxf(acc[r] + 1.0f, 0.0f)) & ~0x1FFu)
                                | (uint32)kc;
                if (pv >= thrF && kc != kG) {
                    if (myc < RCAP) mylist[myc++] = (ushort16_t)kc;
                    else ovf = 1;
                }
            }
        }
        const int totr = myc + __shfl_xor(myc, 32);
        const int aovf = ovf | __shfl_xor(ovf, 32);
        if (aovf) {
            const float zn = znorm_of(zrow);
            float bd = __builtin_inff(); bkf = 0x7FFFFFFF;
            for (int c = 0; c < 16; ++c)
#pragma unroll
                for (int qd = 0; qd < 4; ++qd)
#pragma unroll
                    for (int i = 0; i < 4; ++i) {
                        const int k2c = c * 32 + qd * 8 + h * 4 + i;
                        const float dv = exact_dist(zrow, cb, enl, zn, k2c);
                        if (dv < bd || (dv == bd && k2c < bkf)) { bd = dv; bkf = k2c; }
                    }
            const float obd = __shfl_xor(bd, 32);
            const int   obq = __shfl_xor(bkf, 32);
            if (obd < bd || (obd == bd && obq < bkf)) bkf = obq;
        } else if (totr > 0) {
            const float zn = znorm_of(zrow);
            float bd = __builtin_inff(); bkf = 0x7FFFFFFF;
            if (iown) { bd = exact_dist(zrow, cb, enl, zn, kG); bkf = kG; }
            for (int i = 0; i < myc; ++i) {
                const int k2c = mylist[i];
                const float dv = exact_dist(zrow, cb, enl, zn, k2c);
                if (dv < bd || (dv == bd && k2c < bkf)) { bd = dv; bkf = k2c; }
            }
            const float obd = __shfl_xor(bd, 32);
            const int   obq = __shfl_xor(bkf, 32);
            if (obd < bd || (obd == bd && obq < bkf)) bkf = obq;
        } else {
            bkf = kG;
        }
    } else {
        // ---- common wave: rivals are already in registers ----
        const int k1 = (int)(p1 & 0x1FFu);
        const int k2 = (int)(p2 & 0x1FFu);
        const int r1v = (!iown) && (p1 >= thrF);   // losing half's best (R11 fix)
        const int r2v = (p2 >= thrF);
        const int nr  = r1v + r2v;
        const int totr = nr + __shfl_xor(nr, 32);
        if (totr > 0) {
            const float zn = znorm_of(zrow);
            float bd = __builtin_inff(); bkf = 0x7FFFFFFF;
            if (iown) { bd = exact_dist(zrow, cb, enl, zn, kG); bkf = kG; }
            if (r1v) {
                const float dv = exact_dist(zrow, cb, enl, zn, k1);
                if (dv < bd || (dv == bd && k1 < bkf)) { bd = dv; bkf = k1; }
            }
            if (r2v) {
                const float dv = exact_dist(zrow, cb, enl, zn, k2);
                if (dv < bd || (dv == bd && k2 < bkf)) { bd = dv; bkf = k2; }
            }
            const float obd = __shfl_xor(bd, 32);
            const int   obq = __shfl_xor(bkf, 32);
            if (obd < bd || (obd == bd && obq < bkf)) bkf = obq;
        } else {
            bkf = kG;                     // no rival: screen best is proven
        }
    }

    if (h == 0) {
        sfin[rowl] = bkf;
        idxout[(size_t)b * NT + tbase + rowl] = (float)bkf;
    }
    __syncthreads();

    // ---- staged epilogue: ech build (R8 verbatim) ----
    float* ech = zl;
#pragma unroll
    for (int j = 0; j < 8; ++j) {
        const int qq  = j * 256 + tid;
        const int row = qq >> 4, d4 = qq & 15;
        const float4 v = *(const float4*)(cb + (size_t)sfin[row] * ND + d4 * 4);
        float* dst = &ech[row * ESTR + d4 * 4];
        *(float2*)(dst)     = make_float2(v.x, v.y);
        *(float2*)(dst + 2) = make_float2(v.z, v.w);
    }
    __syncthreads();

    // ---- loss + qout: R15 scalar form (2-way LDS aliasing = free) ----
    double lsum = 0.0;
#pragma unroll 4
    for (int j = 0; j < 32; ++j) {
        const int qq = j * 256 + tid;
        const int ir = qq & 127, d = qq >> 7;
        const float zv = z[zoff + (size_t)d * NT + ir];
        const float ev = ech[ir * ESTR + d];
        const float diff = __fsub_rn(ev, zv);              // quantized - zt
        qout[(size_t)b * (ND*NT) + (size_t)d * NT + tbase + ir] = __fadd_rn(zv, diff);
        lsum += (double)diff * (double)diff;
    }
#pragma unroll
    for (int off = 32; off > 0; off >>= 1) lsum += __shfl_down(lsum, off, 64);
    if ((tid & 63) == 0) sred[tid >> 6] = lsum;
    __syncthreads();

    if (tid == 0) {
        const double bsum = (sred[0] + sred[1]) + (sred[2] + sred[3]);
        atomicAdd(loss_acc + (bi & (NSLOT - 1)), bsum);
        __threadfence();
        const uint32 old = atomicAdd(counter, 1u);
        if (old == (uint32)(NGRID - 1)) {
            __threadfence();
            double tot = 0.0;
            for (int i = 0; i < NSLOT; ++i)
                tot += ((volatile double*)loss_acc)[i];
            const double m = tot / (double)((size_t)NB * NT * ND);
            out0[0] = (float)(1.25 * m);   // codebook + 0.25*commitment
        }
    }
}

extern "C" void kernel_launch(void* const* d_in, const int* in_sizes, int n_in,
                              void* d_out, int out_size, void* d_ws, size_t ws_size,
                              hipStream_t stream) {
    const float* z  = (const float*)d_in[0];
    const float* cb = (const float*)d_in[1];

    float* out      = (float*)d_out;
    float* loss_out = out;                                  // 1 elem
    float* qout     = out + 1;                              // B*D*T
    float* idxout   = out + 1 + (size_t)NB * ND * NT;       // B*T

    // cbfrag 131072 B + 8192 B slack (c=15 prefetch overrun target, unused data)
    uint4*  cbfrag   = (uint4*)d_ws;
    float*  enorm    = (float*)((char*)d_ws + 139264);      // 2048 B
    double* loss_acc = (double*)((char*)d_ws + 141312);     // 16 x 8 B
    uint32* counter  = (uint32*)((char*)d_ws + 141440);     // 4 B

    prep_kernel<<<17, 256, 0, stream>>>(cb, cbfrag, enorm, loss_acc, counter);
    vq_main<<<NGRID, 256, 0, stream>>>(z, cb, cbfrag, enorm, qout, idxout,
                                       loss_acc, counter, loss_out);
}

// Round 10
// 172.442 us; speedup vs baseline: 1.0834x; 1.0214x over previous
//
#include <hip/hip_runtime.h>

#define NB 32
#define ND 64
#define NT 4096
#define NK 512
#define NGRID 1024

typedef __attribute__((ext_vector_type(8))) short short8;
typedef __attribute__((ext_vector_type(16))) float f32x16;
typedef unsigned int uint32;
typedef unsigned short ushort16_t;

#define PERM(r) ((((r) & 7) * 16) + ((r) >> 3))
#define STR 68
// acc-domain margin: bound = emax/2 + 2*eps_dot ~= 1.56e-4 (emax = 64/512^2).
// M2 = 2.5e-4 gives 1.6x safety; packed-quantization (<=6.1e-5) only WIDENS
// collection (round-down superset) and the p3-guard (more fallbacks) - safe.
#define M2 2.5e-4f
#define RCAP 4
#define NSLOT 16

__device__ __forceinline__ ushort16_t bf16rne(float f) {
    uint32 u = __float_as_uint(f);
    return (ushort16_t)((u + 0x7FFFu + ((u >> 16) & 1u)) >> 16);
}
__device__ __forceinline__ float bf16tof(ushort16_t h) {
    return __uint_as_float(((uint32)h) << 16);
}

// ---------------------------------------------------------------------------
// prep (verified R6-R8): blocks 0..15 pack cb into MFMA A-frags (bf16 hi/lo);
// block 16: exact numpy-pairwise enorm + zero loss slots/counter.
// ---------------------------------------------------------------------------
__global__ void prep_kernel(const float* __restrict__ cb,
                            uint4* __restrict__ cbfrag,
                            float* __restrict__ enorm,
                            double* __restrict__ loss_acc,
                            uint32* __restrict__ counter) {
    const int bi = blockIdx.x, tid = threadIdx.x;
    if (bi < 16) {
        const int t = bi * 256 + tid;
        const int c = t >> 8, rem = t & 255, s = rem >> 6, L = rem & 63;
        const int kcode = c * 32 + (L & 31);
        const int dbase = s * 16 + ((L >> 5) << 3);
        const float* src = cb + (size_t)kcode * 64 + dbase;
        const float4 pa = *(const float4*)src;
        const float4 pb = *(const float4*)(src + 4);
        const float f[8] = {pa.x, pa.y, pa.z, pa.w, pb.x, pb.y, pb.z, pb.w};
        uint32 hw[4], lw[4];
#pragma unroll
        for (int i = 0; i < 4; ++i) {
            const ushort16_t h0 = bf16rne(f[2*i]);
            const ushort16_t h1 = bf16rne(f[2*i+1]);
            const ushort16_t l0 = bf16rne(f[2*i]   - bf16tof(h0));
            const ushort16_t l1 = bf16rne(f[2*i+1] - bf16tof(h1));
            hw[i] = (uint32)h0 | ((uint32)h1 << 16);
            lw[i] = (uint32)l0 | ((uint32)l1 << 16);
        }
        cbfrag[(size_t)((c*4+s)*2 + 0)*64 + L] = make_uint4(hw[0],hw[1],hw[2],hw[3]);
        cbfrag[(size_t)((c*4+s)*2 + 1)*64 + L] = make_uint4(lw[0],lw[1],lw[2],lw[3]);
    } else {
        if (tid < NSLOT) loss_acc[tid] = 0.0;
        if (tid == 0) *counter = 0u;
        for (int k = tid; k < NK; k += 256) {
            const float* e = cb + (size_t)k * ND;
            float r[8];
#pragma unroll
            for (int j = 0; j < 8; ++j) {
                float s = __fmul_rn(e[j], e[j]);
#pragma unroll
                for (int i = 1; i < 8; ++i)
                    s = __fadd_rn(s, __fmul_rn(e[8*i+j], e[8*i+j]));
                r[j] = s;
            }
            enorm[k] = __fadd_rn(__fadd_rn(__fadd_rn(r[0],r[1]), __fadd_rn(r[2],r[3])),
                                 __fadd_rn(__fadd_rn(r[4],r[5]), __fadd_rn(r[6],r[7])));
        }
    }
}

// exact dist — the R1-R8 verified bit-exact chain
__device__ __forceinline__ float exact_dist(const float* __restrict__ zrow,
                                            const float* __restrict__ cb,
                                            const float* __restrict__ enl,
                                            float zn, int k2) {
    const float4* e4 = (const float4*)(cb + (size_t)k2 * ND);
    float a = 0.0f;
#pragma unroll
    for (int w = 0; w < 16; ++w) {
        const float4 ev = e4[w];
        const float4 zv = *(const float4*)(zrow + 4 * w);
        a = __builtin_fmaf(zv.x, ev.x, a);
        a = __builtin_fmaf(zv.y, ev.y, a);
        a = __builtin_fmaf(zv.z, ev.z, a);
        a = __builtin_fmaf(zv.w, ev.w, a);
    }
    return __fsub_rn(__fadd_rn(zn, enl[k2]), __fmul_rn(2.0f, a));
}

// lazy znorm: bit-identical to the verified numpy-pairwise chain.
// flat index f = 4*wq + m ascends 0..63 => for each jj = f&7, ii = f>>3
// ascends 0..7 in program order — same summation order as the original.
__device__ __forceinline__ float znorm_of(const float* __restrict__ zrow) {
    float r8[8];
    const float4* zr4 = (const float4*)zrow;
#pragma unroll
    for (int wq = 0; wq < 16; ++wq) {
        const float4 t4 = zr4[wq];
        const float v[4] = {t4.x, t4.y, t4.z, t4.w};
#pragma unroll
        for (int m = 0; m < 4; ++m) {
            const int f = 4 * wq + m;
            const int jj = f & 7;
            if (f < 8) r8[jj] = __fmul_rn(v[m], v[m]);
            else       r8[jj] = __fadd_rn(r8[jj], __fmul_rn(v[m], v[m]));
        }
    }
    return __fadd_rn(__fadd_rn(__fadd_rn(r8[0],r8[1]), __fadd_rn(r8[2],r8[3])),
                     __fadd_rn(__fadd_rn(r8[4],r8[5]), __fadd_rn(r8[6],r8[7])));
}

// ---------------------------------------------------------------------------
// R19 main: R18's screen with (1) top-3 tracking as a min/max sorting network
// (5 v_min/max_u32 vs 8 cmp/cndmask — same multiset semantics, packed values
// totally ordered), and (2) fused loss epilogue: NO ech staging, NO z
// re-read — ev comes straight from L2-resident cb rows (sequential within a
// 128B range -> L1 hits), zv from the still-live zl in LDS (bit-identical to
// global z). One barrier (sfin) instead of two; qout writes stay coalesced.
// ---------------------------------------------------------------------------
__global__ __launch_bounds__(256, 3) void vq_main(const float* __restrict__ z,
                                                  const float* __restrict__ cb,
                                                  const uint4* __restrict__ cbfrag,
                                                  const float* __restrict__ enorm,
                                                  float* __restrict__ qout,
                                                  float* __restrict__ idxout,
                                                  double* __restrict__ loss_acc,
                                                  uint32* __restrict__ counter,
                                                  float* __restrict__ out0) {
    __shared__ __align__(16) char smem[39456];
    float*       zl   = (float*)smem;              // 128 x STR (34816 B), live to end
    float*       enl  = (float*)(smem + 34816);    // 512 f32
    ushort16_t*  cand = (ushort16_t*)(smem + 36864); // 128 x 2 x RCAP u16 = 2048 B
    int*         sfin = (int*)(smem + 38912);      // 128
    double*      sred = (double*)(smem + 39424);   // 4

    const int bi    = blockIdx.x;                  // 1024
    const int b     = bi >> 5;
    const int tbase = (bi & 31) * 128;
    const int tid   = threadIdx.x;
    const size_t zoff = (size_t)b * (ND * NT) + tbase;

    // ---- stage z (verified transpose) ----
#pragma unroll
    for (int j = 0; j < 8; ++j) {
        const int qq = j * 256 + tid;
        const int i4 = qq & 31, d = qq >> 5;
        const float4 v = *(const float4*)(z + zoff + (size_t)d * NT + i4 * 4);
        const float vv[4] = {v.x, v.y, v.z, v.w};
#pragma unroll
        for (int c = 0; c < 4; ++c) {
            const int r = i4 * 4 + c;
            zl[PERM(r) * STR + d] = vv[c];
        }
    }
    for (int k = tid; k < NK; k += 256) enl[k] = enorm[k];
    __syncthreads();

    // ---- B-frags (verified: z rows bf16 hi/lo, same slot->d rule as prep) ----
    const int L    = tid & 63;
    const int w    = tid >> 6;
    const int h    = L >> 5;
    const int rowl = w * 32 + (L & 31);
    short8 bhf[4], blf[4];
    {
        const float* zrow = &zl[PERM(rowl) * STR];
#pragma unroll
        for (int s = 0; s < 4; ++s) {
            const int d0 = s * 16 + h * 8;
            const float4 pa = *(const float4*)(zrow + d0);
            const float4 pb = *(const float4*)(zrow + d0 + 4);
            const float f[8] = {pa.x, pa.y, pa.z, pa.w, pb.x, pb.y, pb.z, pb.w};
            uint32 hw[4], lw[4];
#pragma unroll
            for (int i = 0; i < 4; ++i) {
                const ushort16_t h0 = bf16rne(f[2*i]);
                const ushort16_t h1 = bf16rne(f[2*i+1]);
                const ushort16_t l0 = bf16rne(f[2*i]   - bf16tof(h0));
                const ushort16_t l1 = bf16rne(f[2*i+1] - bf16tof(h1));
                hw[i] = (uint32)h0 | ((uint32)h1 << 16);
                lw[i] = (uint32)l0 | ((uint32)l1 << 16);
            }
            union { uint4 u; short8 s8; } uh, ul;
            uh.u = make_uint4(hw[0],hw[1],hw[2],hw[3]);
            ul.u = make_uint4(lw[0],lw[1],lw[2],lw[3]);
            bhf[s] = uh.s8; blf[s] = ul.s8;
        }
    }

    const int h4 = h * 4;

    // ---- ONE-pass screen: packed top-3 via min/max network, dbuf-prefetched ----
    uint32 p1 = 0u, p2 = 0u, p3 = 0u;   // sorted desc; 0 acts as -inf
    {
        uint4 buf0[8], buf1[8];
#pragma unroll
        for (int p = 0; p < 8; ++p) buf0[p] = cbfrag[(size_t)p * 64 + L];
#pragma unroll 2
        for (int c = 0; c < 16; ++c) {
            const uint4* cur = (c & 1) ? buf1 : buf0;
            uint4*       nxt = (c & 1) ? buf0 : buf1;
#pragma unroll
            for (int p = 0; p < 8; ++p)            // c=15 prefetch hits ws slack
                nxt[p] = cbfrag[(size_t)((c + 1) * 8 + p) * 64 + L];
            f32x16 acc;
#pragma unroll
            for (int r = 0; r < 16; ++r) acc[r] = 0.0f;
#pragma unroll
            for (int s = 0; s < 4; ++s) {
                union { uint4 u; short8 s8; } ah, al;
                ah.u = cur[s * 2 + 0];
                al.u = cur[s * 2 + 1];
                acc = __builtin_amdgcn_mfma_f32_32x32x16_bf16(ah.s8, bhf[s], acc, 0, 0, 0);
                acc = __builtin_amdgcn_mfma_f32_32x32x16_bf16(al.s8, bhf[s], acc, 0, 0, 0);
                acc = __builtin_amdgcn_mfma_f32_32x32x16_bf16(ah.s8, blf[s], acc, 0, 0, 0);
            }
#pragma unroll
            for (int r = 0; r < 16; ++r) {
                const int kc = c * 32 + ((r & 3) + 8 * (r >> 2)) + h4;
                const uint32 pv = (__float_as_uint(fmaxf(acc[r] + 1.0f, 0.0f)) & ~0x1FFu)
                                | (uint32)kc;
                const uint32 lo1 = (pv  < p1) ? pv  : p1;   // min
                p1               = (pv  < p1) ? p1  : pv;   // max
                const uint32 lo2 = (lo1 < p2) ? lo1 : p2;
                p2               = (lo1 < p2) ? p2  : lo1;
                p3               = (lo2 < p3) ? p3  : lo2;
            }
        }
    }

    // ---- cross-half combine + threshold ----
    const uint32 op1 = __shfl_xor(p1, 32);
    const uint32 pkG = (p1 > op1) ? p1 : op1;    // value-ties force rivals below
    const int    kG  = (int)(pkG & 0x1FFu);
    const float  bm   = __uint_as_float(pkG & ~0x1FFu) - 1.0f;
    const float  thrf = bm - M2;
    const uint32 thrF = __float_as_uint(fmaxf(thrf + 1.0f, 0.0f)) & ~0x1FFu;

    const float* zrow = &zl[PERM(rowl) * STR];
    const int    iown = (((kG >> 2) & 1) == h);

    int bkf;
    if (__any((int)(p3 >= thrF))) {
        // ---- rare wave: top-3 may be incomplete -> barrier-free collect ----
        int myc = 0, ovf = 0;
        ushort16_t* mylist = cand + (rowl * 2 + h) * RCAP;
#pragma unroll 1
        for (int c = 0; c < 16; ++c) {
            uint4 B[8];
#pragma unroll
            for (int p = 0; p < 8; ++p) B[p] = cbfrag[(size_t)((c * 8 + p) * 64) + L];
            f32x16 acc;
#pragma unroll
            for (int r = 0; r < 16; ++r) acc[r] = 0.0f;
#pragma unroll
            for (int s = 0; s < 4; ++s) {
                union { uint4 u; short8 s8; } ah, al;
                ah.u = B[s * 2 + 0];
                al.u = B[s * 2 + 1];
                acc = __builtin_amdgcn_mfma_f32_32x32x16_bf16(ah.s8, bhf[s], acc, 0, 0, 0);
                acc = __builtin_amdgcn_mfma_f32_32x32x16_bf16(al.s8, bhf[s], acc, 0, 0, 0);
                acc = __builtin_amdgcn_mfma_f32_32x32x16_bf16(ah.s8, blf[s], acc, 0, 0, 0);
            }
#pragma unroll
            for (int r = 0; r < 16; ++r) {
                const int kc = c * 32 + ((r & 3) + 8 * (r >> 2)) + h4;
                const uint32 pv = (__float_as_uint(fmaxf(acc[r] + 1.0f, 0.0f)) & ~0x1FFu)
                                | (uint32)kc;
                if (pv >= thrF && kc != kG) {
                    if (myc < RCAP) mylist[myc++] = (ushort16_t)kc;
                    else ovf = 1;
                }
            }
        }
        const int totr = myc + __shfl_xor(myc, 32);
        const int aovf = ovf | __shfl_xor(ovf, 32);
        if (aovf) {
            const float zn = znorm_of(zrow);
            float bd = __builtin_inff(); bkf = 0x7FFFFFFF;
            for (int c = 0; c < 16; ++c)
#pragma unroll
                for (int qd = 0; qd < 4; ++qd)
#pragma unroll
                    for (int i = 0; i < 4; ++i) {
                        const int k2c = c * 32 + qd * 8 + h * 4 + i;
                        const float dv = exact_dist(zrow, cb, enl, zn, k2c);
                        if (dv < bd || (dv == bd && k2c < bkf)) { bd = dv; bkf = k2c; }
                    }
            const float obd = __shfl_xor(bd, 32);
            const int   obq = __shfl_xor(bkf, 32);
            if (obd < bd || (obd == bd && obq < bkf)) bkf = obq;
        } else if (totr > 0) {
            const float zn = znorm_of(zrow);
            float bd = __builtin_inff(); bkf = 0x7FFFFFFF;
            if (iown) { bd = exact_dist(zrow, cb, enl, zn, kG); bkf = kG; }
            for (int i = 0; i < myc; ++i) {
                const int k2c = mylist[i];
                const float dv = exact_dist(zrow, cb, enl, zn, k2c);
                if (dv < bd || (dv == bd && k2c < bkf)) { bd = dv; bkf = k2c; }
            }
            const float obd = __shfl_xor(bd, 32);
            const int   obq = __shfl_xor(bkf, 32);
            if (obd < bd || (obd == bd && obq < bkf)) bkf = obq;
        } else {
            bkf = kG;
        }
    } else {
        // ---- common wave: rivals are already in registers ----
        const int k1 = (int)(p1 & 0x1FFu);
        const int k2 = (int)(p2 & 0x1FFu);
        const int r1v = (!iown) && (p1 >= thrF);   // losing half's best (R11 fix)
        const int r2v = (p2 >= thrF);
        const int nr  = r1v + r2v;
        const int totr = nr + __shfl_xor(nr, 32);
        if (totr > 0) {
            const float zn = znorm_of(zrow);
            float bd = __builtin_inff(); bkf = 0x7FFFFFFF;
            if (iown) { bd = exact_dist(zrow, cb, enl, zn, kG); bkf = kG; }
            if (r1v) {
                const float dv = exact_dist(zrow, cb, enl, zn, k1);
                if (dv < bd || (dv == bd && k1 < bkf)) { bd = dv; bkf = k1; }
            }
            if (r2v) {
                const float dv = exact_dist(zrow, cb, enl, zn, k2);
                if (dv < bd || (dv == bd && k2 < bkf)) { bd = dv; bkf = k2; }
            }
            const float obd = __shfl_xor(bd, 32);
            const int   obq = __shfl_xor(bkf, 32);
            if (obd < bd || (obd == bd && obq < bkf)) bkf = obq;
        } else {
            bkf = kG;                     // no rival: screen best is proven
        }
    }

    if (h == 0) {
        sfin[rowl] = bkf;
        idxout[(size_t)b * NT + tbase + rowl] = (float)bkf;
    }
    __syncthreads();

    // ---- fused loss + qout: ev direct from cb (L1/L2), zv from live zl ----
    // thread -> (row ir, d-half): ir = tid&127, d = (tid>>7)*32 + j.
    // qout writes coalesced (128 threads x fixed d = 512B segments);
    // cb row half is 128B sequential per thread -> L1 hits after first touch.
    double lsum = 0.0;
    {
        const int ir   = tid & 127;
        const int dblk = (tid >> 7) * 32;
        const int ksel = sfin[ir];
        const float* crow = cb + (size_t)ksel * ND + dblk;
        const float* zrw  = &zl[PERM(ir) * STR + dblk];
        float* qrow = qout + (size_t)b * (ND*NT) + (size_t)dblk * NT + tbase + ir;
#pragma unroll 4
        for (int j = 0; j < 32; ++j) {
            const float zv = zrw[j];
            const float ev = crow[j];
            const float diff = __fsub_rn(ev, zv);          // quantized - zt
            qrow[(size_t)j * NT] = __fadd_rn(zv, diff);
            lsum += (double)diff * (double)diff;
        }
    }
#pragma unroll
    for (int off = 32; off > 0; off >>= 1) lsum += __shfl_down(lsum, off, 64);
    if ((tid & 63) == 0) sred[tid >> 6] = lsum;
    __syncthreads();

    if (tid == 0) {
        const double bsum = (sred[0] + sred[1]) + (sred[2] + sred[3]);
        atomicAdd(loss_acc + (bi & (NSLOT - 1)), bsum);
        __threadfence();
        const uint32 old = atomicAdd(counter, 1u);
        if (old == (uint32)(NGRID - 1)) {
            __threadfence();
            double tot = 0.0;
            for (int i = 0; i < NSLOT; ++i)
                tot += ((volatile double*)loss_acc)[i];
            const double m = tot / (double)((size_t)NB * NT * ND);
            out0[0] = (float)(1.25 * m);   // codebook + 0.25*commitment
        }
    }
}

extern "C" void kernel_launch(void* const* d_in, const int* in_sizes, int n_in,
                              void* d_out, int out_size, void* d_ws, size_t ws_size,
                              hipStream_t stream) {
    const float* z  = (const float*)d_in[0];
    const float* cb = (const float*)d_in[1];

    float* out      = (float*)d_out;
    float* loss_out = out;                                  // 1 elem
    float* qout     = out + 1;                              // B*D*T
    float* idxout   = out + 1 + (size_t)NB * ND * NT;       // B*T

    // cbfrag 131072 B + 8192 B slack (c=15 prefetch overrun target, unused data)
    uint4*  cbfrag   = (uint4*)d_ws;
    float*  enorm    = (float*)((char*)d_ws + 139264);      // 2048 B
    double* loss_acc = (double*)((char*)d_ws + 141312);     // 16 x 8 B
    uint32* counter  = (uint32*)((char*)d_ws + 141440);     // 4 B

    prep_kernel<<<17, 256, 0, stream>>>(cb, cbfrag, enorm, loss_acc, counter);
    vq_main<<<NGRID, 256, 0, stream>>>(z, cb, cbfrag, enorm, qout, idxout,
                                       loss_acc, counter, loss_out);
}